// Round 8
// baseline (99.543 us; speedup 1.0000x reference)
//
#include <hip/hip_runtime.h>
#include <math.h>

#define SROWS 64   // pool rows per block strip
#define PCH   16   // pool rows per LDS phase
#define QCAP  1024 // k4 compaction queue entries

// ---------------- device helpers ----------------

__device__ __forceinline__ float srgb_to_linear(float x) {
    x = fminf(fmaxf(x, 0.0f), 1.0f);
    return (x <= 0.04045f) ? x * (1.0f / 12.92f)
                           : powf((x + 0.055f) * (1.0f / 1.055f), 2.4f);
}

__device__ __forceinline__ void oklab_ab(float r, float g, float b,
                                         float& A, float& Bc) {
    r = srgb_to_linear(r);
    g = srgb_to_linear(g);
    b = srgb_to_linear(b);
    float l = 0.4122214708f * r + 0.5363325363f * g + 0.0514459929f * b;
    float m = 0.2119034982f * r + 0.6806995451f * g + 0.1073969566f * b;
    float s = 0.0883024619f * r + 0.2817188376f * g + 0.6299787005f * b;
    l = cbrtf(fmaxf(l, 1e-10f));
    m = cbrtf(fmaxf(m, 1e-10f));
    s = cbrtf(fmaxf(s, 1e-10f));
    A  = 1.9779984951f * l - 2.428592205f * m + 0.4505937099f * s;
    Bc = 0.0259040371f * l + 0.7827717662f * m - 0.808675766f  * s;
}

__device__ __forceinline__ void color_terms(const float* __restrict__ pred,
                                            const float* __restrict__ target,
                                            size_t off, size_t HWp, float m,
                                            float& sc, float& sh) {
    float pa, pb, ta, tb;
    oklab_ab(pred[off], pred[off + HWp], pred[off + 2 * HWp], pa, pb);
    oklab_ab(target[off], target[off + HWp], target[off + 2 * HWp], ta, tb);
    float Cp = sqrtf(pa * pa + pb * pb + 1e-12f);
    float Cg = sqrtf(ta * ta + tb * tb + 1e-12f);
    sc += fabsf(Cp - Cg) * m;
    float cosd = (pa * ta + pb * tb) / (Cp * Cg + 1e-12f);
    cosd = fminf(fmaxf(cosd, -1.0f), 1.0f);
    sh += fmaxf(Cg, 0.01f) * (1.0f - cosd) * m;
}

// ---------------- K1: sobel edge_soft, per-pixel-quad row-pair -------------
// One thread computes a float4 of edge output for TWO rows (y0, y0+1).
// All loads (4 rows x 3 channels x {float4 + 2 halo scalars}) are
// independent and issued before compute — no serial row chain, max MLP.
// Block = 256 threads = one full 1024-col row-pair. Grid = B*H/2.
// XCD-swizzled so consecutive row-pairs share an XCD L2 (row reuse = 2x).

__global__ __launch_bounds__(256) void k1_edge(const float* __restrict__ target,
                                               float* __restrict__ edge,
                                               int H, int W, int nblk) {
    int bid = blockIdx.x;
    if ((nblk & 7) == 0) {               // bijective XCD swizzle
        int chunk = nblk >> 3;
        bid = (bid & 7) * chunk + (bid >> 3);
    }
    int pairs = H >> 1;
    int b  = bid / pairs;
    int y0 = (bid % pairs) << 1;         // output rows y0, y0+1
    int t  = threadIdx.x;
    int col0 = t << 2;
    size_t HW = (size_t)H * W;
    const float* tb = target + (size_t)b * 3 * HW;
    float* ep = edge + (size_t)b * HW + col0;

    bool lok = (col0 > 0);
    bool rok = (col0 + 4 < W);

    float4 gA = make_float4(0.f, 0.f, 0.f, 0.f);
    float4 gB = make_float4(0.f, 0.f, 0.f, 0.f);

#pragma unroll
    for (int c = 0; c < 3; ++c) {
        const float* p = tb + (size_t)c * HW;
        float w[4][6];  // rows y0-1..y0+2, cols col0-1..col0+4
#pragma unroll
        for (int r = 0; r < 4; ++r) {
            int y = y0 - 1 + r;
            bool oky = (y >= 0) && (y < H);   // sobel zero-pad
            const float* rowp = p + (size_t)y * W;
            float4 M = oky ? *(const float4*)(rowp + col0)
                           : make_float4(0.f, 0.f, 0.f, 0.f);
            w[r][0] = (oky && lok) ? rowp[col0 - 1] : 0.f;
            w[r][5] = (oky && rok) ? rowp[col0 + 4] : 0.f;
            w[r][1] = M.x; w[r][2] = M.y; w[r][3] = M.z; w[r][4] = M.w;
        }
        float uA[6], vA[6], uB[6], vB[6];
#pragma unroll
        for (int j = 0; j < 6; ++j) {
            uA[j] = fmaf(2.f, w[1][j], w[0][j]) + w[2][j];
            vA[j] = w[2][j] - w[0][j];
            uB[j] = fmaf(2.f, w[2][j], w[1][j]) + w[3][j];
            vB[j] = w[3][j] - w[1][j];
        }
        float gxA[4], gyA[4], gxB[4], gyB[4];
#pragma unroll
        for (int i = 0; i < 4; ++i) {
            gxA[i] = uA[i + 2] - uA[i];
            gyA[i] = fmaf(2.f, vA[i + 1], vA[i]) + vA[i + 2];
            gxB[i] = uB[i + 2] - uB[i];
            gyB[i] = fmaf(2.f, vB[i + 1], vB[i]) + vB[i + 2];
        }
        gA.x = fmaxf(gA.x, fabsf(gxA[0]) + fabsf(gyA[0]));
        gA.y = fmaxf(gA.y, fabsf(gxA[1]) + fabsf(gyA[1]));
        gA.z = fmaxf(gA.z, fabsf(gxA[2]) + fabsf(gyA[2]));
        gA.w = fmaxf(gA.w, fabsf(gxA[3]) + fabsf(gyA[3]));
        gB.x = fmaxf(gB.x, fabsf(gxB[0]) + fabsf(gyB[0]));
        gB.y = fmaxf(gB.y, fabsf(gxB[1]) + fabsf(gyB[1]));
        gB.z = fmaxf(gB.z, fabsf(gxB[2]) + fabsf(gyB[2]));
        gB.w = fmaxf(gB.w, fabsf(gxB[3]) + fabsf(gyB[3]));
    }
    float4 eA, eB;
    eA.x = fminf(2.f * gA.x, 1.f); eA.y = fminf(2.f * gA.y, 1.f);
    eA.z = fminf(2.f * gA.z, 1.f); eA.w = fminf(2.f * gA.w, 1.f);
    eB.x = fminf(2.f * gB.x, 1.f); eB.y = fminf(2.f * gB.y, 1.f);
    eB.z = fminf(2.f * gB.z, 1.f); eB.w = fminf(2.f * gB.w, 1.f);
    *(float4*)(ep + (size_t)y0 * W)       = eA;
    *(float4*)(ep + (size_t)(y0 + 1) * W) = eB;
}

// ---------------- column-strip 2-D pool (vertical in regs, horizontal via LDS) ----

template <int R, bool ISMAX, bool SUB_EDGE>
__global__ __launch_bounds__(256) void pool_kernel(const float* __restrict__ in,
                                                   const float* __restrict__ edge,
                                                   float* __restrict__ out,
                                                   int H, int W) {
    const int OUTW = 256 - 2 * R;
    __shared__ float s_v[PCH][256];
    int cb = (W + OUTW - 1) / OUTW;
    int rs = H / SROWS;
    int blk = blockIdx.x;
    int b   = blk / (cb * rs);
    int t   = blk % (cb * rs);
    int bxi = t / rs, ysi = t % rs;
    int tid = threadIdx.x;
    int col = bxi * OUTW - R + tid;
    int cc  = min(max(col, 0), W - 1);  // replicate == clamped window
    size_t base = (size_t)b * H * W;
    const float* colp = in + base + cc;
    int ys = ysi * SROWS;
    bool writer = (tid >= R) && (tid < OUTW + R) && (col < W);

    for (int ph = 0; ph < SROWS / PCH; ++ph) {
        int y0 = ys + ph * PCH;
        float w[PCH + 2 * R];
#pragma unroll
        for (int k = 0; k < PCH + 2 * R; ++k) {
            int r = min(max(y0 - R + k, 0), H - 1);
            w[k] = colp[(size_t)r * W];
        }
        float v[PCH];
#pragma unroll
        for (int k = 0; k < PCH; ++k) {
            float m = w[k];
#pragma unroll
            for (int d = 1; d <= 2 * R; ++d)
                m = ISMAX ? fmaxf(m, w[k + d]) : fminf(m, w[k + d]);
            v[k] = m;
        }
        __syncthreads();  // previous phase's readers done
#pragma unroll
        for (int k = 0; k < PCH; ++k) s_v[k][tid] = v[k];
        __syncthreads();
        if (writer) {
#pragma unroll
            for (int k = 0; k < PCH; ++k) {
                float m = s_v[k][tid - R];
#pragma unroll
                for (int d = 1; d <= 2 * R; ++d)
                    m = ISMAX ? fmaxf(m, s_v[k][tid - R + d])
                              : fminf(m, s_v[k][tid - R + d]);
                size_t gi = base + (size_t)(y0 + k) * W + col;
                out[gi] = SUB_EDGE ? fmaxf(m - edge[gi], 0.f) : m;
            }
        }
    }
}

// ---------------- K4: 5x5 max-pool + compacted masked OKLab loss ----------------

__global__ __launch_bounds__(256) void k4_loss(const float* __restrict__ pred,
                                               const float* __restrict__ target,
                                               const float* __restrict__ mask0,
                                               float* __restrict__ partials,
                                               int H, int W, int nb) {
    const int R = 2, OUTW = 256 - 2 * R;
    __shared__ float s_v[PCH][256];
    __shared__ int   q_pos[QCAP];
    __shared__ float q_m[QCAP];
    __shared__ int   cnt;
    __shared__ float s_red[3][4];

    int cb = (W + OUTW - 1) / OUTW;
    int rs = H / SROWS;
    int blk = blockIdx.x;
    int b   = blk / (cb * rs);
    int t   = blk % (cb * rs);
    int bxi = t / rs, ysi = t % rs;
    int tid = threadIdx.x;
    int col = bxi * OUTW - R + tid;
    int cc  = min(max(col, 0), W - 1);
    size_t HWp  = (size_t)H * W;
    size_t base = (size_t)b * HWp;
    size_t cbase = (size_t)b * 3 * HWp;
    const float* colp = mask0 + base + cc;
    int ys = ysi * SROWS;
    bool writer = (tid >= R) && (tid < OUTW + R) && (col < W);

    float sm = 0.f, sc = 0.f, sh = 0.f;

    for (int ph = 0; ph < SROWS / PCH; ++ph) {
        int y0 = ys + ph * PCH;
        float w[PCH + 2 * R];
#pragma unroll
        for (int k = 0; k < PCH + 2 * R; ++k) {
            int r = min(max(y0 - R + k, 0), H - 1);
            w[k] = colp[(size_t)r * W];
        }
        float v[PCH];
#pragma unroll
        for (int k = 0; k < PCH; ++k) {
            float m = w[k];
#pragma unroll
            for (int d = 1; d <= 2 * R; ++d) m = fmaxf(m, w[k + d]);
            v[k] = m;
        }
        __syncthreads();  // prev phase queue-processing done
#pragma unroll
        for (int k = 0; k < PCH; ++k) s_v[k][tid] = v[k];
        if (tid == 0) cnt = 0;
        __syncthreads();
        if (writer) {
#pragma unroll
            for (int k = 0; k < PCH; ++k) {
                float m = s_v[k][tid - R];
#pragma unroll
                for (int d = 1; d <= 2 * R; ++d)
                    m = fmaxf(m, s_v[k][tid - R + d]);
                sm += m;
                if (m > 0.f) {
                    int pos = atomicAdd(&cnt, 1);
                    if (pos < QCAP) {
                        q_pos[pos] = ((y0 + k) << 16) | col;
                        q_m[pos] = m;
                    } else {  // overflow fallback (dense mask) — compute inline
                        color_terms(pred, target,
                                    cbase + (size_t)(y0 + k) * W + col,
                                    HWp, m, sc, sh);
                    }
                }
            }
        }
        __syncthreads();
        int n = min(cnt, QCAP);
        for (int i = tid; i < n; i += 256) {
            int pk = q_pos[i];
            color_terms(pred, target,
                        cbase + (size_t)(pk >> 16) * W + (pk & 0xffff),
                        HWp, q_m[i], sc, sh);
        }
    }

    // wave reduce (64 lanes)
#pragma unroll
    for (int off = 32; off > 0; off >>= 1) {
        sm += __shfl_down(sm, off);
        sc += __shfl_down(sc, off);
        sh += __shfl_down(sh, off);
    }
    int lane = tid & 63, wav = tid >> 6;
    __syncthreads();
    if (lane == 0) { s_red[0][wav] = sm; s_red[1][wav] = sc; s_red[2][wav] = sh; }
    __syncthreads();
    if (tid == 0) {
        float tm = 0, tc = 0, th = 0;
        for (int i = 0; i < 4; ++i) {
            tm += s_red[0][i]; tc += s_red[1][i]; th += s_red[2][i];
        }
        partials[blk]          = tm;
        partials[nb + blk]     = tc;
        partials[2 * nb + blk] = th;
    }
}

__global__ void finalize_kernel(const float* __restrict__ partials, int nb,
                                float* __restrict__ out) {
    double sm = 0.0, sc = 0.0, sh = 0.0;
    for (int i = threadIdx.x; i < nb; i += blockDim.x) {
        sm += (double)partials[i];
        sc += (double)partials[nb + i];
        sh += (double)partials[2 * nb + i];
    }
    __shared__ double red[3][256];
    red[0][threadIdx.x] = sm;
    red[1][threadIdx.x] = sc;
    red[2][threadIdx.x] = sh;
    __syncthreads();
    for (int s = blockDim.x / 2; s > 0; s >>= 1) {
        if ((int)threadIdx.x < s) {
            red[0][threadIdx.x] += red[0][threadIdx.x + s];
            red[1][threadIdx.x] += red[1][threadIdx.x + s];
            red[2][threadIdx.x] += red[2][threadIdx.x + s];
        }
        __syncthreads();
    }
    if (threadIdx.x == 0) {
        double ms = fmax(red[0][0], 1.0);
        out[0] = (float)(red[1][0] / ms + 2.0 * red[2][0] / ms);
    }
}

// ---------------- host launch ----------------

extern "C" void kernel_launch(void* const* d_in, const int* in_sizes, int n_in,
                              void* d_out, int out_size, void* d_ws, size_t ws_size,
                              hipStream_t stream) {
    const float* pred   = (const float*)d_in[0];
    const float* target = (const float*)d_in[1];
    float* out = (float*)d_out;

    const int H = 1024, W = 1024;  // fixed problem shape (W==1024 required by k1)
    int Bn = in_sizes[0] / (3 * H * W);
    size_t plane = (size_t)Bn * H * W * sizeof(float);

    char* ws = (char*)d_ws;
    float* planeA = (float*)ws;            // edge, then mask0 (in place)
    float* planeB = (float*)(ws + plane);  // dilated
    float* partials = (float*)(ws + 2 * plane);

    int g1 = Bn * (H / 2);                     // 4096
    int rs = H / SROWS;                        // 16
    int cbP = (W + 245) / 246;                 // 5
    int cb4 = (W + 251) / 252;                 // 5
    int gP = Bn * cbP * rs;
    int g4 = Bn * cb4 * rs;

    // 1. sobel edge_soft -> planeA
    k1_edge<<<g1, 256, 0, stream>>>(target, planeA, H, W, g1);
    // 2. 11x11 max-pool -> planeB (dilated)
    pool_kernel<5, true, false><<<gP, 256, 0, stream>>>(planeA, nullptr, planeB, H, W);
    // 3. 11x11 min-pool + relu(closed - edge) -> planeA in place (mask0)
    pool_kernel<5, false, true><<<gP, 256, 0, stream>>>(planeB, planeA, planeA, H, W);
    // 4. 5x5 max-pool + compacted masked loss -> partials
    k4_loss<<<g4, 256, 0, stream>>>(pred, target, planeA, partials, H, W, g4);
    // 5. final reduce + combine
    finalize_kernel<<<1, 256, 0, stream>>>(partials, g4, out);
}